// Round 1
// baseline (308.726 us; speedup 1.0000x reference)
//
#include <hip/hip_runtime.h>
#include <hip/hip_bf16.h>
#include <math.h>

#define N_ROWS 12288
#define IN_DIM 512
#define F_DIM  128
#define NCHUNK 96          // N_ROWS / 128
#define BM 32
#define BK 32

// ---------------------------------------------------------------------------
// K1: scale[f] = g[f] / ||v[f]||   (w = g*v/||v|| folded into a per-col scale)
// ---------------------------------------------------------------------------
__global__ __launch_bounds__(64) void k1_scale(const float* __restrict__ v,
                                               const float* __restrict__ g,
                                               float* __restrict__ scale) {
    int f = blockIdx.x;
    int lane = threadIdx.x;   // 64 threads = 1 wave
    float sum = 0.f;
    for (int k = lane; k < IN_DIM; k += 64) {
        float x = v[(size_t)f * IN_DIM + k];
        sum += x * x;
    }
    #pragma unroll
    for (int off = 32; off > 0; off >>= 1) sum += __shfl_xor(sum, off);
    if (lane == 0) scale[f] = g[f] / sqrtf(sum);
}

// ---------------------------------------------------------------------------
// K2: z[i][f] = (sum_k x[i][k]*v[f][k]) * scale[f] + b[f]
// Tiled fp32 SGEMM: BM=32 rows x 128 cols per block, BK=32, 256 threads,
// 4x4 micro-tile per thread, LDS transposed tiles for float4 reads.
// ---------------------------------------------------------------------------
__global__ __launch_bounds__(256) void k2_gemm(const float* __restrict__ x,
                                               const float* __restrict__ v,
                                               const float* __restrict__ scale,
                                               const float* __restrict__ b,
                                               float* __restrict__ z) {
    __shared__ float xsT[BK][36];    // [kk][row], stride 36 keeps float4 align
    __shared__ float vsT[BK][132];   // [kk][f],  stride 132 keeps float4 align
    const int t  = threadIdx.x;
    const int tx = t & 31;           // 0..31 -> cols tx*4
    const int ty = t >> 5;           // 0..7  -> rows ty*4
    const int i0 = blockIdx.x * BM;

    float acc[4][4] = {};

    for (int k0 = 0; k0 < IN_DIM; k0 += BK) {
        // stage x tile (32 rows x 32 k), coalesced reads
        #pragma unroll
        for (int l = t; l < BM * BK; l += 256) {
            int row = l >> 5, kk = l & 31;
            xsT[kk][row] = x[(size_t)(i0 + row) * IN_DIM + k0 + kk];
        }
        // stage v tile (128 f x 32 k), coalesced reads
        #pragma unroll
        for (int l = t; l < F_DIM * BK; l += 256) {
            int f = l >> 5, kk = l & 31;
            vsT[kk][f] = v[(size_t)f * IN_DIM + k0 + kk];
        }
        __syncthreads();
        #pragma unroll
        for (int kk = 0; kk < BK; ++kk) {
            float a4[4], b4[4];
            *(float4*)a4 = *(const float4*)&xsT[kk][ty * 4];
            *(float4*)b4 = *(const float4*)&vsT[kk][tx * 4];
            #pragma unroll
            for (int ri = 0; ri < 4; ++ri)
                #pragma unroll
                for (int ci = 0; ci < 4; ++ci)
                    acc[ri][ci] = fmaf(a4[ri], b4[ci], acc[ri][ci]);
        }
        __syncthreads();
    }

    float s4[4], bb4[4];
    *(float4*)s4  = *(const float4*)&scale[tx * 4];
    *(float4*)bb4 = *(const float4*)&b[tx * 4];
    #pragma unroll
    for (int ri = 0; ri < 4; ++ri) {
        int row = i0 + ty * 4 + ri;
        float4 o;
        o.x = fmaf(acc[ri][0], s4[0], bb4[0]);
        o.y = fmaf(acc[ri][1], s4[1], bb4[1]);
        o.z = fmaf(acc[ri][2], s4[2], bb4[2]);
        o.w = fmaf(acc[ri][3], s4[3], bb4[3]);
        *(float4*)&z[(size_t)row * F_DIM + tx * 4] = o;
    }
}

// ---------------------------------------------------------------------------
// K3: s[i] = z[i].a_src ; d[i] = z[i].a_dst   (one wave per row)
// ---------------------------------------------------------------------------
__global__ __launch_bounds__(256) void k3_sd(const float* __restrict__ z,
                                             const float* __restrict__ aw,
                                             float* __restrict__ s,
                                             float* __restrict__ d) {
    int wave = threadIdx.x >> 6;
    int lane = threadIdx.x & 63;
    int i = blockIdx.x * 4 + wave;
    float z0 = z[(size_t)i * F_DIM + lane];
    float z1 = z[(size_t)i * F_DIM + 64 + lane];
    float ss = z0 * aw[lane]          + z1 * aw[64 + lane];
    float dd = z0 * aw[F_DIM + lane]  + z1 * aw[F_DIM + 64 + lane];
    #pragma unroll
    for (int off = 32; off > 0; off >>= 1) {
        ss += __shfl_xor(ss, off);
        dd += __shfl_xor(dd, off);
    }
    if (lane == 0) { s[i] = ss; d[i] = dd; }
}

// ---------------------------------------------------------------------------
// K4a: rank[j] = #{k : d_k < d_j || (d_k==d_j && k<j)}  (brute-force count)
// grid (48, 6): x = j-chunk of 256, y = k-chunk of 2048; atomicAdd partials.
// ---------------------------------------------------------------------------
__global__ __launch_bounds__(256) void k4a_rank(const float* __restrict__ d,
                                                int* __restrict__ rank) {
    __shared__ float ds[2048];
    int j = blockIdx.x * 256 + threadIdx.x;
    float dj = d[j];
    int k0 = blockIdx.y * 2048;
    for (int l = threadIdx.x; l < 2048; l += 256) ds[l] = d[k0 + l];
    __syncthreads();
    int c = 0;
    #pragma unroll 4
    for (int kk = 0; kk < 2048; ++kk) {
        float dk = ds[kk];
        c += (dk < dj) || (dk == dj && (k0 + kk) < j);
    }
    atomicAdd(&rank[j], c);
}

// ---------------------------------------------------------------------------
// K4b: cnt[i] = #{j : d_j <= -s_i}
// ---------------------------------------------------------------------------
__global__ __launch_bounds__(256) void k4b_cnt(const float* __restrict__ s,
                                               const float* __restrict__ d,
                                               int* __restrict__ cnt) {
    __shared__ float ds[2048];
    int i = blockIdx.x * 256 + threadIdx.x;
    float ti = -s[i];
    int k0 = blockIdx.y * 2048;
    for (int l = threadIdx.x; l < 2048; l += 256) ds[l] = d[k0 + l];
    __syncthreads();
    int c = 0;
    #pragma unroll 4
    for (int kk = 0; kk < 2048; ++kk) c += (ds[kk] <= ti);
    atomicAdd(&cnt[i], c);
}

// ---------------------------------------------------------------------------
// K5a: scatter into sorted order: zs[rank[j]][:] = z[j][:], ed[rank[j]]=exp(d_j)
// ---------------------------------------------------------------------------
__global__ __launch_bounds__(128) void k5a_scatter(const float* __restrict__ z,
                                                   const float* __restrict__ d,
                                                   const int* __restrict__ rank,
                                                   float* __restrict__ zs,
                                                   float* __restrict__ ed) {
    int j = blockIdx.x, f = threadIdx.x;
    int r = rank[j];
    zs[(size_t)r * F_DIM + f] = z[(size_t)j * F_DIM + f];
    if (f == 0) ed[r] = expf(d[j]);
}

// ---------------------------------------------------------------------------
// K5b: per-chunk sums (chunk = 128 sorted rows): sum of ed, ed*zs, zs
// ---------------------------------------------------------------------------
__global__ __launch_bounds__(128) void k5b_chunksum(const float* __restrict__ zs,
                                                    const float* __restrict__ ed,
                                                    float* __restrict__ chunkEZ,
                                                    float* __restrict__ chunkZ,
                                                    float* __restrict__ chunkE) {
    int k = blockIdx.x, f = threadIdx.x;
    int p0 = k * 128;
    float aez = 0.f, az = 0.f, ae = 0.f;
    for (int q = 0; q < 128; ++q) {
        float e  = ed[p0 + q];
        float zv = zs[(size_t)(p0 + q) * F_DIM + f];
        aez = fmaf(e, zv, aez);
        az += zv;
        ae += e;
    }
    chunkEZ[k * F_DIM + f] = aez;
    chunkZ [k * F_DIM + f] = az;
    if (f == 0) chunkE[k] = ae;
}

// ---------------------------------------------------------------------------
// K5c: exclusive prefix over the 96 chunk sums (in place), 1 block
// ---------------------------------------------------------------------------
__global__ __launch_bounds__(128) void k5c_chunkprefix(float* __restrict__ chunkEZ,
                                                       float* __restrict__ chunkZ,
                                                       float* __restrict__ chunkE) {
    int f = threadIdx.x;
    float rez = 0.f, rz = 0.f, re = 0.f;
    for (int k = 0; k < NCHUNK; ++k) {
        float vez = chunkEZ[k * F_DIM + f];
        float vz  = chunkZ [k * F_DIM + f];
        chunkEZ[k * F_DIM + f] = rez;
        chunkZ [k * F_DIM + f] = rz;
        rez += vez; rz += vz;
        if (f == 0) { float ve = chunkE[k]; chunkE[k] = re; re += ve; }
    }
}

// ---------------------------------------------------------------------------
// K5d: element-wise exclusive prefixes preE[p], preEZ[p][f], preZ[p][f]
// (index N_ROWS holds the grand totals)
// ---------------------------------------------------------------------------
__global__ __launch_bounds__(128) void k5d_prefix(const float* __restrict__ zs,
                                                  const float* __restrict__ ed,
                                                  const float* __restrict__ chunkEZ,
                                                  const float* __restrict__ chunkZ,
                                                  const float* __restrict__ chunkE,
                                                  float* __restrict__ preEZ,
                                                  float* __restrict__ preZ,
                                                  float* __restrict__ preE) {
    int k = blockIdx.x, f = threadIdx.x;
    float aez = chunkEZ[k * F_DIM + f];
    float az  = chunkZ [k * F_DIM + f];
    float ae  = chunkE[k];
    int p0 = k * 128;
    for (int q = 0; q < 128; ++q) {
        int p = p0 + q;
        preEZ[(size_t)p * F_DIM + f] = aez;
        preZ [(size_t)p * F_DIM + f] = az;
        if (f == 0) preE[p] = ae;
        float e  = ed[p];
        float zv = zs[(size_t)p * F_DIM + f];
        aez = fmaf(e, zv, aez);
        az += zv;
        ae += e;
    }
    if (k == NCHUNK - 1) {
        preEZ[(size_t)N_ROWS * F_DIM + f] = aez;
        preZ [(size_t)N_ROWS * F_DIM + f] = az;
        if (f == 0) preE[N_ROWS] = ae;
    }
}

// ---------------------------------------------------------------------------
// K6: per row i:  z2 = (es*sufEZ + preZ)/ (es*sufE + c) + z ; out = softmax(z2)
// ---------------------------------------------------------------------------
__global__ __launch_bounds__(128) void k6_final(const float* __restrict__ z,
                                                const float* __restrict__ s,
                                                const int* __restrict__ cnt,
                                                const float* __restrict__ preEZ,
                                                const float* __restrict__ preZ,
                                                const float* __restrict__ preE,
                                                float* __restrict__ out) {
    __shared__ float redmx[2], redsum[2];
    int i = blockIdx.x, f = threadIdx.x;
    int wave = f >> 6, lane = f & 63;

    float si = s[i];
    float es = expf(si);
    int   c  = cnt[i];

    float totE = preE[N_ROWS];
    float sufE = totE - preE[c];
    float D = fmaf(es, sufE, (float)c);

    float sufEZ = preEZ[(size_t)N_ROWS * F_DIM + f] - preEZ[(size_t)c * F_DIM + f];
    float num   = fmaf(es, sufEZ, preZ[(size_t)c * F_DIM + f]);
    float z2    = num / D + z[(size_t)i * F_DIM + f];

    // softmax over 128 lanes (2 waves)
    float mx = z2;
    #pragma unroll
    for (int off = 32; off > 0; off >>= 1) mx = fmaxf(mx, __shfl_xor(mx, off));
    if (lane == 0) redmx[wave] = mx;
    __syncthreads();
    mx = fmaxf(redmx[0], redmx[1]);

    float ex = expf(z2 - mx);
    float sm = ex;
    #pragma unroll
    for (int off = 32; off > 0; off >>= 1) sm += __shfl_xor(sm, off);
    if (lane == 0) redsum[wave] = sm;
    __syncthreads();
    sm = redsum[0] + redsum[1];

    out[(size_t)i * F_DIM + f] = ex / sm;
}

// ---------------------------------------------------------------------------
extern "C" void kernel_launch(void* const* d_in, const int* in_sizes, int n_in,
                              void* d_out, int out_size, void* d_ws, size_t ws_size,
                              hipStream_t stream) {
    const float* x  = (const float*)d_in[0];
    const float* v  = (const float*)d_in[1];
    const float* g  = (const float*)d_in[2];
    const float* b  = (const float*)d_in[3];
    const float* aw = (const float*)d_in[4];
    float* out = (float*)d_out;

    float* wsf = (float*)d_ws;
    size_t off = 0;
    float* scale = wsf + off;  off += 128;
    float* z     = wsf + off;  off += (size_t)N_ROWS * F_DIM;
    float* s     = wsf + off;  off += N_ROWS;
    float* d     = wsf + off;  off += N_ROWS;
    int*   rank  = (int*)(wsf + off);  off += N_ROWS;
    int*   cnt   = (int*)(wsf + off);  off += N_ROWS;
    float* ed    = wsf + off;  off += N_ROWS;
    float* zs    = wsf + off;  off += (size_t)N_ROWS * F_DIM;
    float* preE  = wsf + off;  off += N_ROWS + 4;
    float* preEZ = wsf + off;  off += (size_t)(N_ROWS + 1) * F_DIM;
    float* preZ  = wsf + off;  off += (size_t)(N_ROWS + 1) * F_DIM;
    float* chEZ  = wsf + off;  off += NCHUNK * F_DIM;
    float* chZ   = wsf + off;  off += NCHUNK * F_DIM;
    float* chE   = wsf + off;  off += NCHUNK;

    // rank & cnt are atomically accumulated -> zero them (they're adjacent)
    hipMemsetAsync(rank, 0, 2 * N_ROWS * sizeof(int), stream);

    k1_scale<<<F_DIM, 64, 0, stream>>>(v, g, scale);
    k2_gemm<<<N_ROWS / BM, 256, 0, stream>>>(x, v, scale, b, z);
    k3_sd<<<N_ROWS / 4, 256, 0, stream>>>(z, aw, s, d);
    k4a_rank<<<dim3(N_ROWS / 256, 6), 256, 0, stream>>>(d, rank);
    k4b_cnt <<<dim3(N_ROWS / 256, 6), 256, 0, stream>>>(s, d, cnt);
    k5a_scatter<<<N_ROWS, 128, 0, stream>>>(z, d, rank, zs, ed);
    k5b_chunksum<<<NCHUNK, 128, 0, stream>>>(zs, ed, chEZ, chZ, chE);
    k5c_chunkprefix<<<1, 128, 0, stream>>>(chEZ, chZ, chE);
    k5d_prefix<<<NCHUNK, 128, 0, stream>>>(zs, ed, chEZ, chZ, chE, preEZ, preZ, preE);
    k6_final<<<N_ROWS, 128, 0, stream>>>(z, s, cnt, preEZ, preZ, preE, out);
}

// Round 2
// 222.213 us; speedup vs baseline: 1.3893x; 1.3893x over previous
//
#include <hip/hip_runtime.h>
#include <hip/hip_bf16.h>
#include <math.h>

#define N_ROWS 12288
#define IN_DIM 512
#define F_DIM  128
#define CH     64          // sorted-order chunk for prefix pipeline
#define NCH    192         // N_ROWS / CH
#define BM     16
#define BK     32

// ---------------------------------------------------------------------------
// K1: scale[f] = g[f] / ||v[f]||
// ---------------------------------------------------------------------------
__global__ __launch_bounds__(64) void k1_scale(const float* __restrict__ v,
                                               const float* __restrict__ g,
                                               float* __restrict__ scale) {
    int f = blockIdx.x;
    int lane = threadIdx.x;
    float sum = 0.f;
    for (int k = lane; k < IN_DIM; k += 64) {
        float x = v[(size_t)f * IN_DIM + k];
        sum += x * x;
    }
    #pragma unroll
    for (int off = 32; off > 0; off >>= 1) sum += __shfl_xor(sum, off);
    if (lane == 0) scale[f] = g[f] / sqrtf(sum);
}

// ---------------------------------------------------------------------------
// K2: z = x @ (scale*v)^T + b.  BM=16 rows x 128 cols/block, 768 blocks
// (3 blocks/CU -> ~12 waves/CU), 256 threads, 2x4 micro-tile.
// ---------------------------------------------------------------------------
__global__ __launch_bounds__(256) void k2_gemm(const float* __restrict__ x,
                                               const float* __restrict__ v,
                                               const float* __restrict__ scale,
                                               const float* __restrict__ b,
                                               float* __restrict__ z) {
    __shared__ float xsT[BK][BM + 4];      // [kk][row], stride 20
    __shared__ float vsT[BK][F_DIM + 4];   // [kk][f],  stride 132 (16B-align ok)
    const int t  = threadIdx.x;
    const int tx = t & 31;                 // cols tx*4
    const int ty = t >> 5;                 // rows ty*2
    const int i0 = blockIdx.x * BM;

    float acc[2][4] = {};

    for (int k0 = 0; k0 < IN_DIM; k0 += BK) {
        {   // x tile: 16x32 = 512 elems, 2 per thread, coalesced
            int l = t;
            int row = l >> 5, kk = l & 31;
            xsT[kk][row] = x[(size_t)(i0 + row) * IN_DIM + k0 + kk];
            l = t + 256; row = l >> 5; kk = l & 31;
            xsT[kk][row] = x[(size_t)(i0 + row) * IN_DIM + k0 + kk];
        }
        // v tile: 128x32 = 4096 elems, 16 per thread, coalesced
        #pragma unroll
        for (int l = t; l < F_DIM * BK; l += 256) {
            int f = l >> 5, kk = l & 31;
            vsT[kk][f] = v[(size_t)f * IN_DIM + k0 + kk];
        }
        __syncthreads();
        #pragma unroll
        for (int kk = 0; kk < BK; ++kk) {
            float a2[2], b4[4];
            *(float2*)a2 = *(const float2*)&xsT[kk][ty * 2];
            *(float4*)b4 = *(const float4*)&vsT[kk][tx * 4];
            #pragma unroll
            for (int ri = 0; ri < 2; ++ri)
                #pragma unroll
                for (int ci = 0; ci < 4; ++ci)
                    acc[ri][ci] = fmaf(a2[ri], b4[ci], acc[ri][ci]);
        }
        __syncthreads();
    }

    float s4[4], bb4[4];
    *(float4*)s4  = *(const float4*)&scale[tx * 4];
    *(float4*)bb4 = *(const float4*)&b[tx * 4];
    #pragma unroll
    for (int ri = 0; ri < 2; ++ri) {
        int row = i0 + ty * 2 + ri;
        float4 o;
        o.x = fmaf(acc[ri][0], s4[0], bb4[0]);
        o.y = fmaf(acc[ri][1], s4[1], bb4[1]);
        o.z = fmaf(acc[ri][2], s4[2], bb4[2]);
        o.w = fmaf(acc[ri][3], s4[3], bb4[3]);
        *(float4*)&z[(size_t)row * F_DIM + tx * 4] = o;
    }
}

// ---------------------------------------------------------------------------
// K3: s[i] = z[i].a_src ; d[i] = z[i].a_dst   (one wave per row)
// ---------------------------------------------------------------------------
__global__ __launch_bounds__(256) void k3_sd(const float* __restrict__ z,
                                             const float* __restrict__ aw,
                                             float* __restrict__ s,
                                             float* __restrict__ d) {
    int wave = threadIdx.x >> 6;
    int lane = threadIdx.x & 63;
    int i = blockIdx.x * 4 + wave;
    float z0 = z[(size_t)i * F_DIM + lane];
    float z1 = z[(size_t)i * F_DIM + 64 + lane];
    float ss = z0 * aw[lane]         + z1 * aw[64 + lane];
    float dd = z0 * aw[F_DIM + lane] + z1 * aw[F_DIM + 64 + lane];
    #pragma unroll
    for (int off = 32; off > 0; off >>= 1) {
        ss += __shfl_xor(ss, off);
        dd += __shfl_xor(dd, off);
    }
    if (lane == 0) { s[i] = ss; d[i] = dd; }
}

// ---------------------------------------------------------------------------
// K4: merged rank + cnt brute-force counting.
//   rank[j] = #{k : d_k < d_j || (d_k==d_j && k<j)}
//   cnt[j]  = #{k : d_k <= -s_j}
// grid (48, 12): x = j-chunk of 256, y = k-tile of 1024; atomicAdd partials.
// ---------------------------------------------------------------------------
#define K4_TILE 1024
__global__ __launch_bounds__(256) void k4_count(const float* __restrict__ d,
                                                const float* __restrict__ s,
                                                int* __restrict__ rank,
                                                int* __restrict__ cnt) {
    __shared__ float ds[K4_TILE];
    int j = blockIdx.x * 256 + threadIdx.x;
    float dj = d[j];
    float ti = -s[j];
    int k0 = blockIdx.y * K4_TILE;
    for (int l = threadIdx.x; l < K4_TILE; l += 256) ds[l] = d[k0 + l];
    __syncthreads();
    int cr = 0, cc = 0;
    #pragma unroll 2
    for (int kk = 0; kk < K4_TILE; kk += 4) {
        float dv[4];
        *(float4*)dv = *(const float4*)&ds[kk];
        #pragma unroll
        for (int c = 0; c < 4; ++c) {
            float dk = dv[c];
            cr += (dk < dj) || (dk == dj && (k0 + kk + c) < j);
            cc += (dk <= ti);
        }
    }
    atomicAdd(&rank[j], cr);
    atomicAdd(&cnt[j], cc);
}

// ---------------------------------------------------------------------------
// K5a: perm[rank[j]] = j ; ed[rank[j]] = exp(d_j)   (index scatter only)
// ---------------------------------------------------------------------------
__global__ __launch_bounds__(256) void k5a_scatter(const float* __restrict__ d,
                                                   const int* __restrict__ rank,
                                                   int* __restrict__ perm,
                                                   float* __restrict__ ed) {
    int j = blockIdx.x * 256 + threadIdx.x;
    int r = rank[j];
    perm[r] = j;
    ed[r] = expf(d[j]);
}

// ---------------------------------------------------------------------------
// K5b: per-chunk sums over CH=64 sorted rows: sum ed*z[perm], sum z[perm], sum ed
// ---------------------------------------------------------------------------
__global__ __launch_bounds__(128) void k5b_chunksum(const float* __restrict__ z,
                                                    const int* __restrict__ perm,
                                                    const float* __restrict__ ed,
                                                    float* __restrict__ chEZ,
                                                    float* __restrict__ chZ,
                                                    float* __restrict__ chE) {
    int k = blockIdx.x, f = threadIdx.x;
    int p0 = k * CH;
    float aez = 0.f, az = 0.f, ae = 0.f;
    #pragma unroll 4
    for (int q = 0; q < CH; ++q) {
        float e  = ed[p0 + q];
        float zv = z[(size_t)perm[p0 + q] * F_DIM + f];
        aez = fmaf(e, zv, aez);
        az += zv;
        ae += e;
    }
    chEZ[k * F_DIM + f] = aez;
    chZ [k * F_DIM + f] = az;
    if (f == 0) chE[k] = ae;
}

// ---------------------------------------------------------------------------
// K5c: exclusive prefix over the 192 chunk sums — entirely in LDS.
// grid 4 blocks (f-quarters of 32), 128 threads.
// ---------------------------------------------------------------------------
__global__ __launch_bounds__(128) void k5c_chunkprefix(float* __restrict__ chEZ,
                                                       float* __restrict__ chZ,
                                                       float* __restrict__ chE) {
    __shared__ float bEZ[NCH][32];
    __shared__ float bZ [NCH][32];
    __shared__ float bE [NCH];
    int h = blockIdx.x;       // f quarter
    int t = threadIdx.x;
    for (int l = t; l < NCH * 32; l += 128) {
        int k = l >> 5, f = l & 31;
        bEZ[k][f] = chEZ[k * F_DIM + h * 32 + f];
        bZ [k][f] = chZ [k * F_DIM + h * 32 + f];
    }
    if (h == 0) for (int l = t; l < NCH; l += 128) bE[l] = chE[l];
    __syncthreads();
    if (t < 64) {
        // lanes 0..31 scan EZ, 32..63 scan Z (predicated pointer, no divergence)
        float* base = (t < 32) ? &bEZ[0][0] : &bZ[0][0];
        int f = t & 31;
        float r = 0.f;
        #pragma unroll 4
        for (int k = 0; k < NCH; ++k) {
            float vv = base[k * 32 + f];
            base[k * 32 + f] = r;
            r += vv;
        }
    } else if (t == 64 && h == 0) {
        float r = 0.f;
        for (int k = 0; k < NCH; ++k) { float vv = bE[k]; bE[k] = r; r += vv; }
    }
    __syncthreads();
    for (int l = t; l < NCH * 32; l += 128) {
        int k = l >> 5, f = l & 31;
        chEZ[k * F_DIM + h * 32 + f] = bEZ[k][f];
        chZ [k * F_DIM + h * 32 + f] = bZ [k][f];
    }
    if (h == 0) for (int l = t; l < NCH; l += 128) chE[l] = bE[l];
}

// ---------------------------------------------------------------------------
// K5d: element-wise exclusive prefixes preE[p], preEZ[p][f], preZ[p][f].
// grid (NCH, 2 f-halves), 64 threads. preE via wave scan in h==0.
// Index N_ROWS holds grand totals.
// ---------------------------------------------------------------------------
__global__ __launch_bounds__(64) void k5d_prefix(const float* __restrict__ z,
                                                 const int* __restrict__ perm,
                                                 const float* __restrict__ ed,
                                                 const float* __restrict__ chEZ,
                                                 const float* __restrict__ chZ,
                                                 const float* __restrict__ chE,
                                                 float* __restrict__ preEZ,
                                                 float* __restrict__ preZ,
                                                 float* __restrict__ preE) {
    int k = blockIdx.x;        // chunk
    int h = blockIdx.y;        // f half
    int lane = threadIdx.x;
    int f = h * 64 + lane;
    int p0 = k * CH;

    if (h == 0) {
        float e = ed[p0 + lane];
        float incl = e;
        #pragma unroll
        for (int off = 1; off < 64; off <<= 1) {
            float o = __shfl_up(incl, off);
            if (lane >= off) incl += o;
        }
        float base = chE[k];
        preE[p0 + lane] = base + incl - e;
        if (k == NCH - 1 && lane == 63) preE[N_ROWS] = base + incl;
    }

    float aez = chEZ[k * F_DIM + f];
    float az  = chZ [k * F_DIM + f];
    #pragma unroll 4
    for (int q = 0; q < CH; ++q) {
        int p = p0 + q;
        preEZ[(size_t)p * F_DIM + f] = aez;
        preZ [(size_t)p * F_DIM + f] = az;
        float e  = ed[p];
        float zv = z[(size_t)perm[p] * F_DIM + f];
        aez = fmaf(e, zv, aez);
        az += zv;
    }
    if (k == NCH - 1) {
        preEZ[(size_t)N_ROWS * F_DIM + f] = aez;
        preZ [(size_t)N_ROWS * F_DIM + f] = az;
    }
}

// ---------------------------------------------------------------------------
// K6: per row i: z2 = (es*sufEZ + preZ[c]) / (es*sufE + c) + z ; softmax(z2)
// ---------------------------------------------------------------------------
__global__ __launch_bounds__(128) void k6_final(const float* __restrict__ z,
                                                const float* __restrict__ s,
                                                const int* __restrict__ cnt,
                                                const float* __restrict__ preEZ,
                                                const float* __restrict__ preZ,
                                                const float* __restrict__ preE,
                                                float* __restrict__ out) {
    __shared__ float redmx[2], redsum[2];
    int i = blockIdx.x, f = threadIdx.x;
    int wave = f >> 6, lane = f & 63;

    float si = s[i];
    float es = expf(si);
    int   c  = cnt[i];

    float totE = preE[N_ROWS];
    float sufE = totE - preE[c];
    float D = fmaf(es, sufE, (float)c);

    float sufEZ = preEZ[(size_t)N_ROWS * F_DIM + f] - preEZ[(size_t)c * F_DIM + f];
    float num   = fmaf(es, sufEZ, preZ[(size_t)c * F_DIM + f]);
    float z2    = num / D + z[(size_t)i * F_DIM + f];

    float mx = z2;
    #pragma unroll
    for (int off = 32; off > 0; off >>= 1) mx = fmaxf(mx, __shfl_xor(mx, off));
    if (lane == 0) redmx[wave] = mx;
    __syncthreads();
    mx = fmaxf(redmx[0], redmx[1]);

    float ex = expf(z2 - mx);
    float sm = ex;
    #pragma unroll
    for (int off = 32; off > 0; off >>= 1) sm += __shfl_xor(sm, off);
    if (lane == 0) redsum[wave] = sm;
    __syncthreads();
    sm = redsum[0] + redsum[1];

    out[(size_t)i * F_DIM + f] = ex / sm;
}

// ---------------------------------------------------------------------------
extern "C" void kernel_launch(void* const* d_in, const int* in_sizes, int n_in,
                              void* d_out, int out_size, void* d_ws, size_t ws_size,
                              hipStream_t stream) {
    const float* x  = (const float*)d_in[0];
    const float* v  = (const float*)d_in[1];
    const float* g  = (const float*)d_in[2];
    const float* b  = (const float*)d_in[3];
    const float* aw = (const float*)d_in[4];
    float* out = (float*)d_out;

    float* wsf = (float*)d_ws;
    size_t off = 0;
    float* scale = wsf + off;  off += 128;
    float* z     = wsf + off;  off += (size_t)N_ROWS * F_DIM;
    float* s     = wsf + off;  off += N_ROWS;
    float* d     = wsf + off;  off += N_ROWS;
    int*   rank  = (int*)(wsf + off);  off += N_ROWS;   // rank & cnt adjacent:
    int*   cnt   = (int*)(wsf + off);  off += N_ROWS;   // one memset covers both
    int*   perm  = (int*)(wsf + off);  off += N_ROWS;
    float* ed    = wsf + off;  off += N_ROWS;
    float* preE  = wsf + off;  off += N_ROWS + 4;
    float* preEZ = wsf + off;  off += (size_t)(N_ROWS + 1) * F_DIM;
    float* preZ  = wsf + off;  off += (size_t)(N_ROWS + 1) * F_DIM;
    float* chEZ  = wsf + off;  off += NCH * F_DIM;
    float* chZ   = wsf + off;  off += NCH * F_DIM;
    float* chE   = wsf + off;  off += NCH;

    hipMemsetAsync(rank, 0, 2 * N_ROWS * sizeof(int), stream);

    k1_scale<<<F_DIM, 64, 0, stream>>>(v, g, scale);
    k2_gemm<<<N_ROWS / BM, 256, 0, stream>>>(x, v, scale, b, z);
    k3_sd<<<N_ROWS / 4, 256, 0, stream>>>(z, aw, s, d);
    k4_count<<<dim3(N_ROWS / 256, N_ROWS / K4_TILE), 256, 0, stream>>>(d, s, rank, cnt);
    k5a_scatter<<<N_ROWS / 256, 256, 0, stream>>>(d, rank, perm, ed);
    k5b_chunksum<<<NCH, 128, 0, stream>>>(z, perm, ed, chEZ, chZ, chE);
    k5c_chunkprefix<<<4, 128, 0, stream>>>(chEZ, chZ, chE);
    k5d_prefix<<<dim3(NCH, 2), 64, 0, stream>>>(z, perm, ed, chEZ, chZ, chE, preEZ, preZ, preE);
    k6_final<<<N_ROWS, 128, 0, stream>>>(z, s, cnt, preEZ, preZ, preE, out);
}

// Round 3
// 196.571 us; speedup vs baseline: 1.5706x; 1.1304x over previous
//
#include <hip/hip_runtime.h>
#include <hip/hip_bf16.h>
#include <math.h>

#define N_ROWS 12288
#define IN_DIM 512
#define F_DIM  128
#define CH     32          // sorted-order chunk for prefix pipeline
#define NCH    384         // N_ROWS / CH
#define K4T    2048        // k-tile for rank counting

typedef unsigned short ushort_t;
typedef __attribute__((ext_vector_type(8))) short bf16x8;
typedef __attribute__((ext_vector_type(4))) float f32x4;

__device__ __forceinline__ unsigned orderKey(float x) {
    unsigned b = __float_as_uint(x);
    return (b & 0x80000000u) ? ~b : (b | 0x80000000u);
}

// ---------------------------------------------------------------------------
// K1: per-feature norm + scale, fold scale into v, split to bf16 hi/lo.
// grid 128 blocks x 64 threads (one wave per feature row).
// ---------------------------------------------------------------------------
__global__ __launch_bounds__(64) void k1_prep(const float* __restrict__ v,
                                              const float* __restrict__ g,
                                              ushort_t* __restrict__ vh,
                                              ushort_t* __restrict__ vl) {
    int f = blockIdx.x;
    int lane = threadIdx.x;
    float sum = 0.f;
    for (int k = lane; k < IN_DIM; k += 64) {
        float x = v[(size_t)f * IN_DIM + k];
        sum += x * x;
    }
    #pragma unroll
    for (int off = 32; off > 0; off >>= 1) sum += __shfl_xor(sum, off);
    float sc = g[f] / sqrtf(sum);          // all lanes have full sum
    for (int k = lane; k < IN_DIM; k += 64) {
        float w = v[(size_t)f * IN_DIM + k] * sc;
        __hip_bfloat16 hb = __float2bfloat16(w);
        float hf = __bfloat162float(hb);
        __hip_bfloat16 lb = __float2bfloat16(w - hf);
        vh[(size_t)f * IN_DIM + k] = *(ushort_t*)&hb;
        vl[(size_t)f * IN_DIM + k] = *(ushort_t*)&lb;
    }
}

// ---------------------------------------------------------------------------
// K2: z = x @ w^T + b via bf16x3 split MFMA (16x16x32).
// Block: M=32 rows x N=128 cols, BK=64, 256 threads (4 waves),
// wave w covers n in [w*32, w*32+32), 2x2 tiles of 16x16 per wave.
// ---------------------------------------------------------------------------
#define LDSS 72   // LDS row stride in bf16 elems (144B = 9*16B, b128-aligned)
__global__ __launch_bounds__(256) void k2_mfma(const float* __restrict__ x,
                                               const ushort_t* __restrict__ vh,
                                               const ushort_t* __restrict__ vl,
                                               const float* __restrict__ b,
                                               float* __restrict__ z) {
    __shared__ ushort_t sh[(32 + 32 + 128 + 128) * LDSS];
    ushort_t* xh_s = sh;
    ushort_t* xl_s = sh + 32 * LDSS;
    ushort_t* vh_s = sh + 64 * LDSS;
    ushort_t* vl_s = sh + (64 + 128) * LDSS;

    const int t = threadIdx.x;
    const int wave = t >> 6, lane = t & 63;
    const int i0 = blockIdx.x * 32;
    const int n0 = wave * 32;
    const int r8 = t >> 3;   // 0..31
    const int kg = t & 7;    // 0..7

    f32x4 acc[2][2] = {};    // [mt][nt]

    for (int k0 = 0; k0 < IN_DIM; k0 += 64) {
        // stage x tile (32 rows x 64 k): thread -> row r8, cols kg*8..+7
        {
            const float* gp = &x[(size_t)(i0 + r8) * IN_DIM + k0 + kg * 8];
            float4 f0 = *(const float4*)gp;
            float4 f1 = *(const float4*)(gp + 4);
            float ff[8] = {f0.x, f0.y, f0.z, f0.w, f1.x, f1.y, f1.z, f1.w};
            ushort_t h[8], lo[8];
            #pragma unroll
            for (int e = 0; e < 8; ++e) {
                __hip_bfloat16 hb = __float2bfloat16(ff[e]);
                float hf = __bfloat162float(hb);
                __hip_bfloat16 lb = __float2bfloat16(ff[e] - hf);
                h[e]  = *(ushort_t*)&hb;
                lo[e] = *(ushort_t*)&lb;
            }
            *(uint4*)&xh_s[r8 * LDSS + kg * 8] = *(uint4*)h;
            *(uint4*)&xl_s[r8 * LDSS + kg * 8] = *(uint4*)lo;
        }
        // stage v tile (128 rows x 64 k): 1024 groups of 8, 4 per thread
        #pragma unroll
        for (int it = 0; it < 4; ++it) {
            int gidx = t + it * 256;
            int row = gidx >> 3, kgg = gidx & 7;
            uint4 hv = *(const uint4*)&vh[(size_t)row * IN_DIM + k0 + kgg * 8];
            uint4 lv = *(const uint4*)&vl[(size_t)row * IN_DIM + k0 + kgg * 8];
            *(uint4*)&vh_s[row * LDSS + kgg * 8] = hv;
            *(uint4*)&vl_s[row * LDSS + kgg * 8] = lv;
        }
        __syncthreads();
        #pragma unroll
        for (int sub = 0; sub < 2; ++sub) {
            int kb = sub * 32 + (lane >> 4) * 8;
            bf16x8 ah[2], al[2], bh[2], bl[2];
            #pragma unroll
            for (int mt = 0; mt < 2; ++mt) {
                int row = mt * 16 + (lane & 15);
                ah[mt] = *(const bf16x8*)&xh_s[row * LDSS + kb];
                al[mt] = *(const bf16x8*)&xl_s[row * LDSS + kb];
            }
            #pragma unroll
            for (int nt = 0; nt < 2; ++nt) {
                int row = n0 + nt * 16 + (lane & 15);
                bh[nt] = *(const bf16x8*)&vh_s[row * LDSS + kb];
                bl[nt] = *(const bf16x8*)&vl_s[row * LDSS + kb];
            }
            #pragma unroll
            for (int mt = 0; mt < 2; ++mt)
                #pragma unroll
                for (int nt = 0; nt < 2; ++nt) {
                    acc[mt][nt] = __builtin_amdgcn_mfma_f32_16x16x32_bf16(ah[mt], bh[nt], acc[mt][nt], 0, 0, 0);
                    acc[mt][nt] = __builtin_amdgcn_mfma_f32_16x16x32_bf16(ah[mt], bl[nt], acc[mt][nt], 0, 0, 0);
                    acc[mt][nt] = __builtin_amdgcn_mfma_f32_16x16x32_bf16(al[mt], bh[nt], acc[mt][nt], 0, 0, 0);
                }
        }
        __syncthreads();
    }
    // epilogue: C row=(lane>>4)*4+r (m), col=lane&15 (n); add bias, store fp32
    #pragma unroll
    for (int nt = 0; nt < 2; ++nt) {
        int n = n0 + nt * 16 + (lane & 15);
        float bb = b[n];
        #pragma unroll
        for (int mt = 0; mt < 2; ++mt)
            #pragma unroll
            for (int r = 0; r < 4; ++r) {
                int m = i0 + mt * 16 + (lane >> 4) * 4 + r;
                z[(size_t)m * F_DIM + n] = acc[mt][nt][r] + bb;
            }
    }
}

// ---------------------------------------------------------------------------
// K3: s[i], d[i] dot products + packed sort key (orderable(d)<<32 | i)
// ---------------------------------------------------------------------------
__global__ __launch_bounds__(256) void k3_sd(const float* __restrict__ z,
                                             const float* __restrict__ aw,
                                             float* __restrict__ s,
                                             float* __restrict__ d,
                                             unsigned long long* __restrict__ keys) {
    int wave = threadIdx.x >> 6;
    int lane = threadIdx.x & 63;
    int i = blockIdx.x * 4 + wave;
    float z0 = z[(size_t)i * F_DIM + lane];
    float z1 = z[(size_t)i * F_DIM + 64 + lane];
    float ss = z0 * aw[lane]         + z1 * aw[64 + lane];
    float dd = z0 * aw[F_DIM + lane] + z1 * aw[F_DIM + 64 + lane];
    #pragma unroll
    for (int off = 32; off > 0; off >>= 1) {
        ss += __shfl_xor(ss, off);
        dd += __shfl_xor(dd, off);
    }
    if (lane == 0) {
        s[i] = ss;
        d[i] = dd;
        keys[i] = ((unsigned long long)orderKey(dd) << 32) | (unsigned)i;
    }
}

// ---------------------------------------------------------------------------
// K4: rank[j] = #{k : key_k < key_j}. Streamed from global (uniform address
// -> L1 broadcast), one u64 compare per element. grid (48, 6), atomic partials.
// ---------------------------------------------------------------------------
__global__ __launch_bounds__(256) void k4_rank(const unsigned long long* __restrict__ keys,
                                               int* __restrict__ rank) {
    int j = blockIdx.x * 256 + threadIdx.x;
    unsigned long long kj = keys[j];
    const unsigned long long* p = keys + blockIdx.y * K4T;
    int c = 0;
    #pragma unroll 4
    for (int kk = 0; kk < K4T; kk += 2) {
        unsigned long long a = p[kk];
        unsigned long long bq = p[kk + 1];
        c += (a < kj);
        c += (bq < kj);
    }
    atomicAdd(&rank[j], c);
}

// ---------------------------------------------------------------------------
// K5a: scatter into sorted order: perm, ed = exp(d), soi = orderable key
// ---------------------------------------------------------------------------
__global__ __launch_bounds__(256) void k5a_scatter(const float* __restrict__ d,
                                                   const int* __restrict__ rank,
                                                   int* __restrict__ perm,
                                                   float* __restrict__ ed,
                                                   unsigned* __restrict__ soi) {
    int j = blockIdx.x * 256 + threadIdx.x;
    int r = rank[j];
    float dj = d[j];
    perm[r] = j;
    ed[r] = expf(dj);
    soi[r] = orderKey(dj);
}

// ---------------------------------------------------------------------------
// K5e: cnt[i] = #{p : soi[p] <= orderable(-s_i)} via binary search
// ---------------------------------------------------------------------------
__global__ __launch_bounds__(256) void k5e_cnt(const float* __restrict__ s,
                                               const unsigned* __restrict__ soi,
                                               int* __restrict__ cnt) {
    int i = blockIdx.x * 256 + threadIdx.x;
    unsigned ot = orderKey(-s[i]);
    int lo = 0, hi = N_ROWS;
    while (lo < hi) {
        int mid = (lo + hi) >> 1;
        if (soi[mid] <= ot) lo = mid + 1; else hi = mid;
    }
    cnt[i] = lo;
}

// ---------------------------------------------------------------------------
// K5b: per-chunk sums over CH=32 sorted rows
// ---------------------------------------------------------------------------
__global__ __launch_bounds__(128) void k5b_chunksum(const float* __restrict__ z,
                                                    const int* __restrict__ perm,
                                                    const float* __restrict__ ed,
                                                    float* __restrict__ chEZ,
                                                    float* __restrict__ chZ,
                                                    float* __restrict__ chE) {
    int k = blockIdx.x, f = threadIdx.x;
    int p0 = k * CH;
    float aez = 0.f, az = 0.f, ae = 0.f;
    #pragma unroll 4
    for (int q = 0; q < CH; ++q) {
        float e  = ed[p0 + q];
        float zv = z[(size_t)perm[p0 + q] * F_DIM + f];
        aez = fmaf(e, zv, aez);
        az += zv;
        ae += e;
    }
    chEZ[k * F_DIM + f] = aez;
    chZ [k * F_DIM + f] = az;
    if (f == 0) chE[k] = ae;
}

// ---------------------------------------------------------------------------
// K5c: exclusive prefix over NCH=384 chunk sums. grid 129 x 64:
// blocks 0..127 scan one f-column of chEZ and chZ; block 128 scans chE.
// Each lane owns 6 chunks; wave-scan combines.
// ---------------------------------------------------------------------------
__global__ __launch_bounds__(64) void k5c_scan(float* __restrict__ chEZ,
                                               float* __restrict__ chZ,
                                               float* __restrict__ chE) {
    int bx = blockIdx.x;
    int lane = threadIdx.x;
    if (bx < F_DIM) {
        float* arr[2] = {chEZ, chZ};
        #pragma unroll
        for (int a = 0; a < 2; ++a) {
            float vv[6];
            #pragma unroll
            for (int e = 0; e < 6; ++e)
                vv[e] = arr[a][(lane * 6 + e) * F_DIM + bx];
            float run = 0.f;
            #pragma unroll
            for (int e = 0; e < 6; ++e) { float tmp = vv[e]; vv[e] = run; run += tmp; }
            float incl = run;
            #pragma unroll
            for (int off = 1; off < 64; off <<= 1) {
                float o = __shfl_up(incl, off);
                if (lane >= off) incl += o;
            }
            float excl = incl - run;
            #pragma unroll
            for (int e = 0; e < 6; ++e)
                arr[a][(lane * 6 + e) * F_DIM + bx] = excl + vv[e];
        }
    } else {
        float vv[6];
        #pragma unroll
        for (int e = 0; e < 6; ++e) vv[e] = chE[lane * 6 + e];
        float run = 0.f;
        #pragma unroll
        for (int e = 0; e < 6; ++e) { float tmp = vv[e]; vv[e] = run; run += tmp; }
        float incl = run;
        #pragma unroll
        for (int off = 1; off < 64; off <<= 1) {
            float o = __shfl_up(incl, off);
            if (lane >= off) incl += o;
        }
        float excl = incl - run;
        #pragma unroll
        for (int e = 0; e < 6; ++e) chE[lane * 6 + e] = excl + vv[e];
    }
}

// ---------------------------------------------------------------------------
// K5d: element-level exclusive prefixes preE, preEZ, preZ. grid NCH x 128.
// Index N_ROWS holds grand totals.
// ---------------------------------------------------------------------------
__global__ __launch_bounds__(128) void k5d_prefix(const float* __restrict__ z,
                                                  const int* __restrict__ perm,
                                                  const float* __restrict__ ed,
                                                  const float* __restrict__ chEZ,
                                                  const float* __restrict__ chZ,
                                                  const float* __restrict__ chE,
                                                  float* __restrict__ preEZ,
                                                  float* __restrict__ preZ,
                                                  float* __restrict__ preE) {
    int k = blockIdx.x;
    int f = threadIdx.x;
    int p0 = k * CH;

    if (f < CH) {   // lanes 0..31 of wave 0: scan ed within chunk
        float e = ed[p0 + f];
        float incl = e;
        #pragma unroll
        for (int off = 1; off < 32; off <<= 1) {
            float o = __shfl_up(incl, off);
            if (f >= off) incl += o;
        }
        float base = chE[k];
        preE[p0 + f] = base + incl - e;
        if (k == NCH - 1 && f == CH - 1) preE[N_ROWS] = base + incl;
    }

    float aez = chEZ[k * F_DIM + f];
    float az  = chZ [k * F_DIM + f];
    #pragma unroll 4
    for (int q = 0; q < CH; ++q) {
        int p = p0 + q;
        preEZ[(size_t)p * F_DIM + f] = aez;
        preZ [(size_t)p * F_DIM + f] = az;
        float e  = ed[p];
        float zv = z[(size_t)perm[p] * F_DIM + f];
        aez = fmaf(e, zv, aez);
        az += zv;
    }
    if (k == NCH - 1) {
        preEZ[(size_t)N_ROWS * F_DIM + f] = aez;
        preZ [(size_t)N_ROWS * F_DIM + f] = az;
    }
}

// ---------------------------------------------------------------------------
// K6: z2 = (es*sufEZ + preZ[c]) / (es*sufE + c) + z ; out = softmax(z2)
// ---------------------------------------------------------------------------
__global__ __launch_bounds__(128) void k6_final(const float* __restrict__ z,
                                                const float* __restrict__ s,
                                                const int* __restrict__ cnt,
                                                const float* __restrict__ preEZ,
                                                const float* __restrict__ preZ,
                                                const float* __restrict__ preE,
                                                float* __restrict__ out) {
    __shared__ float redmx[2], redsum[2];
    int i = blockIdx.x, f = threadIdx.x;
    int wave = f >> 6, lane = f & 63;

    float si = s[i];
    float es = expf(si);
    int   c  = cnt[i];

    float totE = preE[N_ROWS];
    float sufE = totE - preE[c];
    float D = fmaf(es, sufE, (float)c);

    float sufEZ = preEZ[(size_t)N_ROWS * F_DIM + f] - preEZ[(size_t)c * F_DIM + f];
    float num   = fmaf(es, sufEZ, preZ[(size_t)c * F_DIM + f]);
    float z2    = num / D + z[(size_t)i * F_DIM + f];

    float mx = z2;
    #pragma unroll
    for (int off = 32; off > 0; off >>= 1) mx = fmaxf(mx, __shfl_xor(mx, off));
    if (lane == 0) redmx[wave] = mx;
    __syncthreads();
    mx = fmaxf(redmx[0], redmx[1]);

    float ex = expf(z2 - mx);
    float sm = ex;
    #pragma unroll
    for (int off = 32; off > 0; off >>= 1) sm += __shfl_xor(sm, off);
    if (lane == 0) redsum[wave] = sm;
    __syncthreads();
    sm = redsum[0] + redsum[1];

    out[(size_t)i * F_DIM + f] = ex / sm;
}

// ---------------------------------------------------------------------------
extern "C" void kernel_launch(void* const* d_in, const int* in_sizes, int n_in,
                              void* d_out, int out_size, void* d_ws, size_t ws_size,
                              hipStream_t stream) {
    const float* x  = (const float*)d_in[0];
    const float* v  = (const float*)d_in[1];
    const float* g  = (const float*)d_in[2];
    const float* b  = (const float*)d_in[3];
    const float* aw = (const float*)d_in[4];
    float* out = (float*)d_out;

    float* wsf = (float*)d_ws;
    size_t off = 0;
    float* z     = wsf + off;  off += (size_t)N_ROWS * F_DIM;
    float* s     = wsf + off;  off += N_ROWS;
    float* d     = wsf + off;  off += N_ROWS;
    unsigned long long* keys = (unsigned long long*)(wsf + off);  off += 2 * N_ROWS;  // 16B-aligned
    int*   rank  = (int*)(wsf + off);  off += N_ROWS;
    int*   cnt   = (int*)(wsf + off);  off += N_ROWS;
    int*   perm  = (int*)(wsf + off);  off += N_ROWS;
    float* ed    = wsf + off;  off += N_ROWS;
    unsigned* soi = (unsigned*)(wsf + off);  off += N_ROWS;
    float* preE  = wsf + off;  off += N_ROWS + 4;
    float* preEZ = wsf + off;  off += (size_t)(N_ROWS + 1) * F_DIM;
    float* preZ  = wsf + off;  off += (size_t)(N_ROWS + 1) * F_DIM;
    float* chEZ  = wsf + off;  off += NCH * F_DIM;
    float* chZ   = wsf + off;  off += NCH * F_DIM;
    float* chE   = wsf + off;  off += NCH;
    ushort_t* vh = (ushort_t*)(wsf + off);  off += (F_DIM * IN_DIM) / 2;
    ushort_t* vl = (ushort_t*)(wsf + off);  off += (F_DIM * IN_DIM) / 2;

    hipMemsetAsync(rank, 0, N_ROWS * sizeof(int), stream);

    k1_prep<<<F_DIM, 64, 0, stream>>>(v, g, vh, vl);
    k2_mfma<<<N_ROWS / 32, 256, 0, stream>>>(x, vh, vl, b, z);
    k3_sd<<<N_ROWS / 4, 256, 0, stream>>>(z, aw, s, d, keys);
    k4_rank<<<dim3(N_ROWS / 256, N_ROWS / K4T), 256, 0, stream>>>(keys, rank);
    k5a_scatter<<<N_ROWS / 256, 256, 0, stream>>>(d, rank, perm, ed, soi);
    k5e_cnt<<<N_ROWS / 256, 256, 0, stream>>>(s, soi, cnt);
    k5b_chunksum<<<NCH, 128, 0, stream>>>(z, perm, ed, chEZ, chZ, chE);
    k5c_scan<<<F_DIM + 1, 64, 0, stream>>>(chEZ, chZ, chE);
    k5d_prefix<<<NCH, 128, 0, stream>>>(z, perm, ed, chEZ, chZ, chE, preEZ, preZ, preE);
    k6_final<<<N_ROWS, 128, 0, stream>>>(z, s, cnt, preEZ, preZ, preE, out);
}

// Round 4
// 150.914 us; speedup vs baseline: 2.0457x; 1.3025x over previous
//
#include <hip/hip_runtime.h>
#include <hip/hip_bf16.h>
#include <math.h>

#define N_ROWS 12288
#define IN_DIM 512
#define F_DIM  128
#define CH     32          // sorted-order chunk for prefix pipeline
#define NCH    384         // N_ROWS / CH
#define K4T    512         // k-tile for rank counting

typedef unsigned short ushort_t;
typedef __attribute__((ext_vector_type(8))) short bf16x8;
typedef __attribute__((ext_vector_type(4))) float f32x4;

__device__ __forceinline__ unsigned orderKey(float x) {
    unsigned b = __float_as_uint(x);
    return (b & 0x80000000u) ? ~b : (b | 0x80000000u);
}

// ---------------------------------------------------------------------------
// K1: per-feature norm + scale, fold scale into v, split to bf16 hi/lo.
// ---------------------------------------------------------------------------
__global__ __launch_bounds__(64) void k1_prep(const float* __restrict__ v,
                                              const float* __restrict__ g,
                                              ushort_t* __restrict__ vh,
                                              ushort_t* __restrict__ vl) {
    int f = blockIdx.x;
    int lane = threadIdx.x;
    float sum = 0.f;
    for (int k = lane; k < IN_DIM; k += 64) {
        float x = v[(size_t)f * IN_DIM + k];
        sum += x * x;
    }
    #pragma unroll
    for (int off = 32; off > 0; off >>= 1) sum += __shfl_xor(sum, off);
    float sc = g[f] / sqrtf(sum);
    for (int k = lane; k < IN_DIM; k += 64) {
        float w = v[(size_t)f * IN_DIM + k] * sc;
        __hip_bfloat16 hb = __float2bfloat16(w);
        float hf = __bfloat162float(hb);
        __hip_bfloat16 lb = __float2bfloat16(w - hf);
        vh[(size_t)f * IN_DIM + k] = *(ushort_t*)&hb;
        vl[(size_t)f * IN_DIM + k] = *(ushort_t*)&lb;
    }
}

// ---------------------------------------------------------------------------
// K2: z = x @ w^T + b via bf16x3 split MFMA (16x16x32).
// Block: M=16 rows x N=128 cols, BK=64, 256 threads (4 waves),
// wave w covers n in [w*32, w*32+32), 768 blocks -> 3 blocks/CU (LDS 41.5KB).
// ---------------------------------------------------------------------------
#define LDSS 72   // LDS row stride in bf16 elems (144B = 9*16B)
__global__ __launch_bounds__(256) void k2_mfma(const float* __restrict__ x,
                                               const ushort_t* __restrict__ vh,
                                               const ushort_t* __restrict__ vl,
                                               const float* __restrict__ b,
                                               float* __restrict__ z) {
    __shared__ ushort_t sh[(16 + 16 + 128 + 128) * LDSS];
    ushort_t* xh_s = sh;
    ushort_t* xl_s = sh + 16 * LDSS;
    ushort_t* vh_s = sh + 32 * LDSS;
    ushort_t* vl_s = sh + (32 + 128) * LDSS;

    const int t = threadIdx.x;
    const int wave = t >> 6, lane = t & 63;
    const int i0 = blockIdx.x * 16;
    const int n0 = wave * 32;
    const int r16 = t >> 4;   // 0..15 (x row)
    const int kg4 = t & 15;   // 0..15 -> x cols kg4*4

    f32x4 acc[2] = {};        // [nt]

    for (int k0 = 0; k0 < IN_DIM; k0 += 64) {
        {   // x tile 16 x 64: 4 floats per thread, split hi/lo
            float4 f0 = *(const float4*)&x[(size_t)(i0 + r16) * IN_DIM + k0 + kg4 * 4];
            float ff[4] = {f0.x, f0.y, f0.z, f0.w};
            ushort_t h[4], lo[4];
            #pragma unroll
            for (int e = 0; e < 4; ++e) {
                __hip_bfloat16 hb = __float2bfloat16(ff[e]);
                float hf = __bfloat162float(hb);
                __hip_bfloat16 lb = __float2bfloat16(ff[e] - hf);
                h[e]  = *(ushort_t*)&hb;
                lo[e] = *(ushort_t*)&lb;
            }
            *(uint2*)&xh_s[r16 * LDSS + kg4 * 4] = *(uint2*)h;
            *(uint2*)&xl_s[r16 * LDSS + kg4 * 4] = *(uint2*)lo;
        }
        // v tile 128 x 64: 1024 groups of 8 bf16, 4 per thread
        #pragma unroll
        for (int it = 0; it < 4; ++it) {
            int gidx = t + it * 256;
            int row = gidx >> 3, kgg = gidx & 7;
            uint4 hv = *(const uint4*)&vh[(size_t)row * IN_DIM + k0 + kgg * 8];
            uint4 lv = *(const uint4*)&vl[(size_t)row * IN_DIM + k0 + kgg * 8];
            *(uint4*)&vh_s[row * LDSS + kgg * 8] = hv;
            *(uint4*)&vl_s[row * LDSS + kgg * 8] = lv;
        }
        __syncthreads();
        #pragma unroll
        for (int sub = 0; sub < 2; ++sub) {
            int kb = sub * 32 + (lane >> 4) * 8;
            int mrow = lane & 15;
            bf16x8 ah = *(const bf16x8*)&xh_s[mrow * LDSS + kb];
            bf16x8 al = *(const bf16x8*)&xl_s[mrow * LDSS + kb];
            bf16x8 bh[2], bl[2];
            #pragma unroll
            for (int nt = 0; nt < 2; ++nt) {
                int row = n0 + nt * 16 + (lane & 15);
                bh[nt] = *(const bf16x8*)&vh_s[row * LDSS + kb];
                bl[nt] = *(const bf16x8*)&vl_s[row * LDSS + kb];
            }
            #pragma unroll
            for (int nt = 0; nt < 2; ++nt) {
                acc[nt] = __builtin_amdgcn_mfma_f32_16x16x32_bf16(ah, bh[nt], acc[nt], 0, 0, 0);
                acc[nt] = __builtin_amdgcn_mfma_f32_16x16x32_bf16(ah, bl[nt], acc[nt], 0, 0, 0);
                acc[nt] = __builtin_amdgcn_mfma_f32_16x16x32_bf16(al, bh[nt], acc[nt], 0, 0, 0);
            }
        }
        __syncthreads();
    }
    // epilogue: C row=(lane>>4)*4+r (m), col=lane&15 (n)
    #pragma unroll
    for (int nt = 0; nt < 2; ++nt) {
        int n = n0 + nt * 16 + (lane & 15);
        float bb = b[n];
        #pragma unroll
        for (int r = 0; r < 4; ++r) {
            int m = i0 + (lane >> 4) * 4 + r;
            z[(size_t)m * F_DIM + n] = acc[nt][r] + bb;
        }
    }
}

// ---------------------------------------------------------------------------
// K3: s[i], d[i] dot products + packed sort key (orderable(d)<<32 | i)
// ---------------------------------------------------------------------------
__global__ __launch_bounds__(256) void k3_sd(const float* __restrict__ z,
                                             const float* __restrict__ aw,
                                             float* __restrict__ s,
                                             float* __restrict__ d,
                                             unsigned long long* __restrict__ keys) {
    int wave = threadIdx.x >> 6;
    int lane = threadIdx.x & 63;
    int i = blockIdx.x * 4 + wave;
    float z0 = z[(size_t)i * F_DIM + lane];
    float z1 = z[(size_t)i * F_DIM + 64 + lane];
    float ss = z0 * aw[lane]         + z1 * aw[64 + lane];
    float dd = z0 * aw[F_DIM + lane] + z1 * aw[F_DIM + 64 + lane];
    #pragma unroll
    for (int off = 32; off > 0; off >>= 1) {
        ss += __shfl_xor(ss, off);
        dd += __shfl_xor(dd, off);
    }
    if (lane == 0) {
        s[i] = ss;
        d[i] = dd;
        keys[i] = ((unsigned long long)orderKey(dd) << 32) | (unsigned)i;
    }
}

// ---------------------------------------------------------------------------
// K4: rank[j] = #{k : key_k < key_j}  AND  cnt[j] = #{k : okey_k <= okey(-s_j)}
// in one pass. Keys batched 8 at a time (uniform -> s_load_dwordx16);
// grid (48, 24) = 1152 blocks = 4.5 blocks/CU, 18 waves/CU.
// ---------------------------------------------------------------------------
__global__ __launch_bounds__(256) void k4_rank(const unsigned long long* __restrict__ keys,
                                               const float* __restrict__ s,
                                               int* __restrict__ rank,
                                               int* __restrict__ cnt) {
    int j = blockIdx.x * 256 + threadIdx.x;
    unsigned long long kj = keys[j];
    unsigned ti = orderKey(-s[j]);
    const unsigned long long* p = keys + blockIdx.y * K4T;
    int cr = 0, cc = 0;
    for (int kk = 0; kk < K4T; kk += 8) {
        unsigned long long kv[8];
        #pragma unroll
        for (int e = 0; e < 8; ++e) kv[e] = p[kk + e];
        #pragma unroll
        for (int e = 0; e < 8; ++e) {
            cr += (kv[e] < kj);
            cc += ((unsigned)(kv[e] >> 32) <= ti);
        }
    }
    atomicAdd(&rank[j], cr);
    atomicAdd(&cnt[j], cc);
}

// ---------------------------------------------------------------------------
// K5a: scatter into sorted order: perm[rank[j]] = j ; ed[rank[j]] = exp(d_j)
// ---------------------------------------------------------------------------
__global__ __launch_bounds__(256) void k5a_scatter(const float* __restrict__ d,
                                                   const int* __restrict__ rank,
                                                   int* __restrict__ perm,
                                                   float* __restrict__ ed) {
    int j = blockIdx.x * 256 + threadIdx.x;
    int r = rank[j];
    perm[r] = j;
    ed[r] = expf(d[j]);
}

// ---------------------------------------------------------------------------
// K5b: per-chunk sums over CH=32 sorted rows
// ---------------------------------------------------------------------------
__global__ __launch_bounds__(128) void k5b_chunksum(const float* __restrict__ z,
                                                    const int* __restrict__ perm,
                                                    const float* __restrict__ ed,
                                                    float* __restrict__ chEZ,
                                                    float* __restrict__ chZ,
                                                    float* __restrict__ chE) {
    int k = blockIdx.x, f = threadIdx.x;
    int p0 = k * CH;
    float aez = 0.f, az = 0.f, ae = 0.f;
    #pragma unroll 4
    for (int q = 0; q < CH; ++q) {
        float e  = ed[p0 + q];
        float zv = z[(size_t)perm[p0 + q] * F_DIM + f];
        aez = fmaf(e, zv, aez);
        az += zv;
        ae += e;
    }
    chEZ[k * F_DIM + f] = aez;
    chZ [k * F_DIM + f] = az;
    if (f == 0) chE[k] = ae;
}

// ---------------------------------------------------------------------------
// K5c: exclusive prefix over NCH=384 chunk sums. grid 129 x 64:
// blocks 0..127 scan one f-column of chEZ and chZ; block 128 scans chE.
// ---------------------------------------------------------------------------
__global__ __launch_bounds__(64) void k5c_scan(float* __restrict__ chEZ,
                                               float* __restrict__ chZ,
                                               float* __restrict__ chE) {
    int bx = blockIdx.x;
    int lane = threadIdx.x;
    if (bx < F_DIM) {
        float* arr[2] = {chEZ, chZ};
        #pragma unroll
        for (int a = 0; a < 2; ++a) {
            float vv[6];
            #pragma unroll
            for (int e = 0; e < 6; ++e)
                vv[e] = arr[a][(lane * 6 + e) * F_DIM + bx];
            float run = 0.f;
            #pragma unroll
            for (int e = 0; e < 6; ++e) { float tmp = vv[e]; vv[e] = run; run += tmp; }
            float incl = run;
            #pragma unroll
            for (int off = 1; off < 64; off <<= 1) {
                float o = __shfl_up(incl, off);
                if (lane >= off) incl += o;
            }
            float excl = incl - run;
            #pragma unroll
            for (int e = 0; e < 6; ++e)
                arr[a][(lane * 6 + e) * F_DIM + bx] = excl + vv[e];
        }
    } else {
        float vv[6];
        #pragma unroll
        for (int e = 0; e < 6; ++e) vv[e] = chE[lane * 6 + e];
        float run = 0.f;
        #pragma unroll
        for (int e = 0; e < 6; ++e) { float tmp = vv[e]; vv[e] = run; run += tmp; }
        float incl = run;
        #pragma unroll
        for (int off = 1; off < 64; off <<= 1) {
            float o = __shfl_up(incl, off);
            if (lane >= off) incl += o;
        }
        float excl = incl - run;
        #pragma unroll
        for (int e = 0; e < 6; ++e) chE[lane * 6 + e] = excl + vv[e];
    }
}

// ---------------------------------------------------------------------------
// K5d: element-level exclusive prefixes preE, preEZ, preZ. grid NCH x 128.
// Index N_ROWS holds grand totals.
// ---------------------------------------------------------------------------
__global__ __launch_bounds__(128) void k5d_prefix(const float* __restrict__ z,
                                                  const int* __restrict__ perm,
                                                  const float* __restrict__ ed,
                                                  const float* __restrict__ chEZ,
                                                  const float* __restrict__ chZ,
                                                  const float* __restrict__ chE,
                                                  float* __restrict__ preEZ,
                                                  float* __restrict__ preZ,
                                                  float* __restrict__ preE) {
    int k = blockIdx.x;
    int f = threadIdx.x;
    int p0 = k * CH;

    if (f < CH) {   // lanes 0..31 of wave 0: scan ed within chunk
        float e = ed[p0 + f];
        float incl = e;
        #pragma unroll
        for (int off = 1; off < 32; off <<= 1) {
            float o = __shfl_up(incl, off);
            if (f >= off) incl += o;
        }
        float base = chE[k];
        preE[p0 + f] = base + incl - e;
        if (k == NCH - 1 && f == CH - 1) preE[N_ROWS] = base + incl;
    }

    float aez = chEZ[k * F_DIM + f];
    float az  = chZ [k * F_DIM + f];
    #pragma unroll 4
    for (int q = 0; q < CH; ++q) {
        int p = p0 + q;
        preEZ[(size_t)p * F_DIM + f] = aez;
        preZ [(size_t)p * F_DIM + f] = az;
        float e  = ed[p];
        float zv = z[(size_t)perm[p] * F_DIM + f];
        aez = fmaf(e, zv, aez);
        az += zv;
    }
    if (k == NCH - 1) {
        preEZ[(size_t)N_ROWS * F_DIM + f] = aez;
        preZ [(size_t)N_ROWS * F_DIM + f] = az;
    }
}

// ---------------------------------------------------------------------------
// K6: z2 = (es*sufEZ + preZ[c]) / (es*sufE + c) + z ; out = softmax(z2)
// ---------------------------------------------------------------------------
__global__ __launch_bounds__(128) void k6_final(const float* __restrict__ z,
                                                const float* __restrict__ s,
                                                const int* __restrict__ cnt,
                                                const float* __restrict__ preEZ,
                                                const float* __restrict__ preZ,
                                                const float* __restrict__ preE,
                                                float* __restrict__ out) {
    __shared__ float redmx[2], redsum[2];
    int i = blockIdx.x, f = threadIdx.x;
    int wave = f >> 6, lane = f & 63;

    float si = s[i];
    float es = expf(si);
    int   c  = cnt[i];

    float totE = preE[N_ROWS];
    float sufE = totE - preE[c];
    float D = fmaf(es, sufE, (float)c);

    float sufEZ = preEZ[(size_t)N_ROWS * F_DIM + f] - preEZ[(size_t)c * F_DIM + f];
    float num   = fmaf(es, sufEZ, preZ[(size_t)c * F_DIM + f]);
    float z2    = num / D + z[(size_t)i * F_DIM + f];

    float mx = z2;
    #pragma unroll
    for (int off = 32; off > 0; off >>= 1) mx = fmaxf(mx, __shfl_xor(mx, off));
    if (lane == 0) redmx[wave] = mx;
    __syncthreads();
    mx = fmaxf(redmx[0], redmx[1]);

    float ex = expf(z2 - mx);
    float sm = ex;
    #pragma unroll
    for (int off = 32; off > 0; off >>= 1) sm += __shfl_xor(sm, off);
    if (lane == 0) redsum[wave] = sm;
    __syncthreads();
    sm = redsum[0] + redsum[1];

    out[(size_t)i * F_DIM + f] = ex / sm;
}

// ---------------------------------------------------------------------------
extern "C" void kernel_launch(void* const* d_in, const int* in_sizes, int n_in,
                              void* d_out, int out_size, void* d_ws, size_t ws_size,
                              hipStream_t stream) {
    const float* x  = (const float*)d_in[0];
    const float* v  = (const float*)d_in[1];
    const float* g  = (const float*)d_in[2];
    const float* b  = (const float*)d_in[3];
    const float* aw = (const float*)d_in[4];
    float* out = (float*)d_out;

    float* wsf = (float*)d_ws;
    size_t off = 0;
    float* z     = wsf + off;  off += (size_t)N_ROWS * F_DIM;
    float* s     = wsf + off;  off += N_ROWS;
    float* d     = wsf + off;  off += N_ROWS;
    unsigned long long* keys = (unsigned long long*)(wsf + off);  off += 2 * N_ROWS;
    int*   rank  = (int*)(wsf + off);  off += N_ROWS;   // rank & cnt adjacent:
    int*   cnt   = (int*)(wsf + off);  off += N_ROWS;   // one memset covers both
    int*   perm  = (int*)(wsf + off);  off += N_ROWS;
    float* ed    = wsf + off;  off += N_ROWS;
    float* preE  = wsf + off;  off += N_ROWS + 4;
    float* preEZ = wsf + off;  off += (size_t)(N_ROWS + 1) * F_DIM;
    float* preZ  = wsf + off;  off += (size_t)(N_ROWS + 1) * F_DIM;
    float* chEZ  = wsf + off;  off += NCH * F_DIM;
    float* chZ   = wsf + off;  off += NCH * F_DIM;
    float* chE   = wsf + off;  off += NCH;
    ushort_t* vh = (ushort_t*)(wsf + off);  off += (F_DIM * IN_DIM) / 2;
    ushort_t* vl = (ushort_t*)(wsf + off);  off += (F_DIM * IN_DIM) / 2;

    hipMemsetAsync(rank, 0, 2 * N_ROWS * sizeof(int), stream);

    k1_prep<<<F_DIM, 64, 0, stream>>>(v, g, vh, vl);
    k2_mfma<<<N_ROWS / 16, 256, 0, stream>>>(x, vh, vl, b, z);
    k3_sd<<<N_ROWS / 4, 256, 0, stream>>>(z, aw, s, d, keys);
    k4_rank<<<dim3(N_ROWS / 256, N_ROWS / K4T), 256, 0, stream>>>(keys, s, rank, cnt);
    k5a_scatter<<<N_ROWS / 256, 256, 0, stream>>>(d, rank, perm, ed);
    k5b_chunksum<<<NCH, 128, 0, stream>>>(z, perm, ed, chEZ, chZ, chE);
    k5c_scan<<<F_DIM + 1, 64, 0, stream>>>(chEZ, chZ, chE);
    k5d_prefix<<<NCH, 128, 0, stream>>>(z, perm, ed, chEZ, chZ, chE, preEZ, preZ, preE);
    k6_final<<<N_ROWS, 128, 0, stream>>>(z, s, cnt, preEZ, preZ, preE, out);
}

// Round 5
// 145.655 us; speedup vs baseline: 2.1196x; 1.0361x over previous
//
#include <hip/hip_runtime.h>
#include <hip/hip_bf16.h>
#include <math.h>

#define N_ROWS 12288
#define IN_DIM 512
#define F_DIM  128
#define CH     32          // sorted-order chunk for prefix pipeline
#define NCH    384         // N_ROWS / CH
#define K4T    512         // k-tile for rank counting

typedef unsigned short ushort_t;
typedef __attribute__((ext_vector_type(8))) short bf16x8;
typedef __attribute__((ext_vector_type(4))) float f32x4;

__device__ __forceinline__ unsigned orderKey(float x) {
    unsigned b = __float_as_uint(x);
    return (b & 0x80000000u) ? ~b : (b | 0x80000000u);
}

// ---------------------------------------------------------------------------
// K1: per-feature norm + scale, fold scale into v, split to bf16 hi/lo.
// ---------------------------------------------------------------------------
__global__ __launch_bounds__(64) void k1_prep(const float* __restrict__ v,
                                              const float* __restrict__ g,
                                              ushort_t* __restrict__ vh,
                                              ushort_t* __restrict__ vl) {
    int f = blockIdx.x;
    int lane = threadIdx.x;
    float sum = 0.f;
    for (int k = lane; k < IN_DIM; k += 64) {
        float x = v[(size_t)f * IN_DIM + k];
        sum += x * x;
    }
    #pragma unroll
    for (int off = 32; off > 0; off >>= 1) sum += __shfl_xor(sum, off);
    float sc = g[f] / sqrtf(sum);
    for (int k = lane; k < IN_DIM; k += 64) {
        float w = v[(size_t)f * IN_DIM + k] * sc;
        __hip_bfloat16 hb = __float2bfloat16(w);
        float hf = __bfloat162float(hb);
        __hip_bfloat16 lb = __float2bfloat16(w - hf);
        vh[(size_t)f * IN_DIM + k] = *(ushort_t*)&hb;
        vl[(size_t)f * IN_DIM + k] = *(ushort_t*)&lb;
    }
}

// ---------------------------------------------------------------------------
// K2: z = x @ w^T + b via bf16x3 split MFMA (16x16x32), FUSED with:
//   - s/d dot products + sort keys (k3)  [block owns full F_DIM for its rows]
//   - zeroing of rank/cnt for its row slice (replaces memset)
// Block: M=32 rows x N=128 cols, BK=64, 512 threads (8 waves, n-tile 16/wave),
// 384 blocks, LDS 46 KB -> 3 blocks/CU cap.
// ---------------------------------------------------------------------------
#define LDSS 72   // LDS row stride in bf16 elems (144B = 9*16B)
__global__ __launch_bounds__(512) void k2_mfma(const float* __restrict__ x,
                                               const ushort_t* __restrict__ vh,
                                               const ushort_t* __restrict__ vl,
                                               const float* __restrict__ b,
                                               const float* __restrict__ aw,
                                               float* __restrict__ z,
                                               float* __restrict__ s,
                                               float* __restrict__ d,
                                               unsigned long long* __restrict__ keys,
                                               int* __restrict__ rank,
                                               int* __restrict__ cnt) {
    __shared__ ushort_t sh[(32 + 32 + 128 + 128) * LDSS];   // 46080 B
    ushort_t* xh_s = sh;
    ushort_t* xl_s = sh + 32 * LDSS;
    ushort_t* vh_s = sh + 64 * LDSS;
    ushort_t* vl_s = sh + (64 + 128) * LDSS;

    const int t = threadIdx.x;
    const int wave = t >> 6, lane = t & 63;
    const int i0 = blockIdx.x * 32;
    const int n0 = wave * 16;
    const int rx  = t >> 4;   // 0..31 (x row)
    const int kg4 = t & 15;   // x cols kg4*4

    f32x4 acc[2] = {};        // [mt]

    if (t < 32) rank[i0 + t] = 0;
    else if (t < 64) cnt[i0 + t - 32] = 0;

    for (int k0 = 0; k0 < IN_DIM; k0 += 64) {
        {   // x tile 32 x 64: 4 floats per thread, split hi/lo
            float4 f0 = *(const float4*)&x[(size_t)(i0 + rx) * IN_DIM + k0 + kg4 * 4];
            float ff[4] = {f0.x, f0.y, f0.z, f0.w};
            ushort_t h[4], lo[4];
            #pragma unroll
            for (int e = 0; e < 4; ++e) {
                __hip_bfloat16 hb = __float2bfloat16(ff[e]);
                float hf = __bfloat162float(hb);
                __hip_bfloat16 lb = __float2bfloat16(ff[e] - hf);
                h[e]  = *(ushort_t*)&hb;
                lo[e] = *(ushort_t*)&lb;
            }
            *(uint2*)&xh_s[rx * LDSS + kg4 * 4] = *(uint2*)h;
            *(uint2*)&xl_s[rx * LDSS + kg4 * 4] = *(uint2*)lo;
        }
        // v tile 128 x 64 (hi+lo): 1024 groups of 8 bf16 each, 2 per thread
        #pragma unroll
        for (int it = 0; it < 2; ++it) {
            int gidx = t + it * 512;
            int row = gidx >> 3, kgg = gidx & 7;
            uint4 hv = *(const uint4*)&vh[(size_t)row * IN_DIM + k0 + kgg * 8];
            uint4 lv = *(const uint4*)&vl[(size_t)row * IN_DIM + k0 + kgg * 8];
            *(uint4*)&vh_s[row * LDSS + kgg * 8] = hv;
            *(uint4*)&vl_s[row * LDSS + kgg * 8] = lv;
        }
        __syncthreads();
        #pragma unroll
        for (int sub = 0; sub < 2; ++sub) {
            int kb = sub * 32 + (lane >> 4) * 8;
            int nrow = n0 + (lane & 15);
            bf16x8 bh = *(const bf16x8*)&vh_s[nrow * LDSS + kb];
            bf16x8 bl = *(const bf16x8*)&vl_s[nrow * LDSS + kb];
            #pragma unroll
            for (int mt = 0; mt < 2; ++mt) {
                int mrow = mt * 16 + (lane & 15);
                bf16x8 ah = *(const bf16x8*)&xh_s[mrow * LDSS + kb];
                bf16x8 al = *(const bf16x8*)&xl_s[mrow * LDSS + kb];
                acc[mt] = __builtin_amdgcn_mfma_f32_16x16x32_bf16(ah, bh, acc[mt], 0, 0, 0);
                acc[mt] = __builtin_amdgcn_mfma_f32_16x16x32_bf16(ah, bl, acc[mt], 0, 0, 0);
                acc[mt] = __builtin_amdgcn_mfma_f32_16x16x32_bf16(al, bh, acc[mt], 0, 0, 0);
            }
        }
        __syncthreads();
    }

    // ---- epilogue: bias add, store z, and keep tile in LDS for s/d ----
    float* zt = (float*)sh;          // 32 x 132 f32 = 16896 B (reuse staging LDS)
    {
        int n = n0 + (lane & 15);
        float bb = b[n];
        #pragma unroll
        for (int mt = 0; mt < 2; ++mt)
            #pragma unroll
            for (int r = 0; r < 4; ++r) {
                int mrow = mt * 16 + (lane >> 4) * 4 + r;
                float val = acc[mt][r] + bb;
                z[(size_t)(i0 + mrow) * F_DIM + n] = val;
                zt[mrow * 132 + n] = val;
            }
    }
    __syncthreads();
    // s/d/keys: 8 waves x 4 rows each; 64 lanes cover 128 f (2 per lane)
    float awS0 = aw[lane], awS1 = aw[64 + lane];
    float awD0 = aw[F_DIM + lane], awD1 = aw[F_DIM + 64 + lane];
    #pragma unroll
    for (int rr = 0; rr < 4; ++rr) {
        int row = wave * 4 + rr;
        float z0 = zt[row * 132 + lane];
        float z1 = zt[row * 132 + 64 + lane];
        float ss = z0 * awS0 + z1 * awS1;
        float dd = z0 * awD0 + z1 * awD1;
        #pragma unroll
        for (int off = 32; off > 0; off >>= 1) {
            ss += __shfl_xor(ss, off);
            dd += __shfl_xor(dd, off);
        }
        if (lane == 0) {
            int i = i0 + row;
            s[i] = ss;
            d[i] = dd;
            keys[i] = ((unsigned long long)orderKey(dd) << 32) | (unsigned)i;
        }
    }
}

// ---------------------------------------------------------------------------
// K4: rank[j] = #{k : key_k < key_j}  AND  cnt[j] = #{k : okey_k <= okey(-s_j)}
// in one pass. Keys batched 8 at a time; grid (48, 24) = 1152 blocks.
// ---------------------------------------------------------------------------
__global__ __launch_bounds__(256) void k4_rank(const unsigned long long* __restrict__ keys,
                                               const float* __restrict__ s,
                                               int* __restrict__ rank,
                                               int* __restrict__ cnt) {
    int j = blockIdx.x * 256 + threadIdx.x;
    unsigned long long kj = keys[j];
    unsigned ti = orderKey(-s[j]);
    const unsigned long long* p = keys + blockIdx.y * K4T;
    int cr = 0, cc = 0;
    for (int kk = 0; kk < K4T; kk += 8) {
        unsigned long long kv[8];
        #pragma unroll
        for (int e = 0; e < 8; ++e) kv[e] = p[kk + e];
        #pragma unroll
        for (int e = 0; e < 8; ++e) {
            cr += (kv[e] < kj);
            cc += ((unsigned)(kv[e] >> 32) <= ti);
        }
    }
    atomicAdd(&rank[j], cr);
    atomicAdd(&cnt[j], cc);
}

// ---------------------------------------------------------------------------
// K5a: scatter into sorted order: perm[rank[j]] = j ; ed[rank[j]] = exp(d_j)
// ---------------------------------------------------------------------------
__global__ __launch_bounds__(256) void k5a_scatter(const float* __restrict__ d,
                                                   const int* __restrict__ rank,
                                                   int* __restrict__ perm,
                                                   float* __restrict__ ed) {
    int j = blockIdx.x * 256 + threadIdx.x;
    int r = rank[j];
    perm[r] = j;
    ed[r] = expf(d[j]);
}

// ---------------------------------------------------------------------------
// K5b: per-chunk sums over CH=32 sorted rows
// ---------------------------------------------------------------------------
__global__ __launch_bounds__(128) void k5b_chunksum(const float* __restrict__ z,
                                                    const int* __restrict__ perm,
                                                    const float* __restrict__ ed,
                                                    float* __restrict__ chEZ,
                                                    float* __restrict__ chZ,
                                                    float* __restrict__ chE) {
    int k = blockIdx.x, f = threadIdx.x;
    int p0 = k * CH;
    float aez = 0.f, az = 0.f, ae = 0.f;
    #pragma unroll 4
    for (int q = 0; q < CH; ++q) {
        float e  = ed[p0 + q];
        float zv = z[(size_t)perm[p0 + q] * F_DIM + f];
        aez = fmaf(e, zv, aez);
        az += zv;
        ae += e;
    }
    chEZ[k * F_DIM + f] = aez;
    chZ [k * F_DIM + f] = az;
    if (f == 0) chE[k] = ae;
}

// ---------------------------------------------------------------------------
// K5c: exclusive prefix over NCH=384 chunk sums. grid 129 x 64.
// ---------------------------------------------------------------------------
__global__ __launch_bounds__(64) void k5c_scan(float* __restrict__ chEZ,
                                               float* __restrict__ chZ,
                                               float* __restrict__ chE) {
    int bx = blockIdx.x;
    int lane = threadIdx.x;
    if (bx < F_DIM) {
        float* arr[2] = {chEZ, chZ};
        #pragma unroll
        for (int a = 0; a < 2; ++a) {
            float vv[6];
            #pragma unroll
            for (int e = 0; e < 6; ++e)
                vv[e] = arr[a][(lane * 6 + e) * F_DIM + bx];
            float run = 0.f;
            #pragma unroll
            for (int e = 0; e < 6; ++e) { float tmp = vv[e]; vv[e] = run; run += tmp; }
            float incl = run;
            #pragma unroll
            for (int off = 1; off < 64; off <<= 1) {
                float o = __shfl_up(incl, off);
                if (lane >= off) incl += o;
            }
            float excl = incl - run;
            #pragma unroll
            for (int e = 0; e < 6; ++e)
                arr[a][(lane * 6 + e) * F_DIM + bx] = excl + vv[e];
        }
    } else {
        float vv[6];
        #pragma unroll
        for (int e = 0; e < 6; ++e) vv[e] = chE[lane * 6 + e];
        float run = 0.f;
        #pragma unroll
        for (int e = 0; e < 6; ++e) { float tmp = vv[e]; vv[e] = run; run += tmp; }
        float incl = run;
        #pragma unroll
        for (int off = 1; off < 64; off <<= 1) {
            float o = __shfl_up(incl, off);
            if (lane >= off) incl += o;
        }
        float excl = incl - run;
        #pragma unroll
        for (int e = 0; e < 6; ++e) chE[lane * 6 + e] = excl + vv[e];
    }
}

// ---------------------------------------------------------------------------
// K5d: element-level exclusive prefixes preE, preEZ, preZ. grid NCH x 128.
// ---------------------------------------------------------------------------
__global__ __launch_bounds__(128) void k5d_prefix(const float* __restrict__ z,
                                                  const int* __restrict__ perm,
                                                  const float* __restrict__ ed,
                                                  const float* __restrict__ chEZ,
                                                  const float* __restrict__ chZ,
                                                  const float* __restrict__ chE,
                                                  float* __restrict__ preEZ,
                                                  float* __restrict__ preZ,
                                                  float* __restrict__ preE) {
    int k = blockIdx.x;
    int f = threadIdx.x;
    int p0 = k * CH;

    if (f < CH) {
        float e = ed[p0 + f];
        float incl = e;
        #pragma unroll
        for (int off = 1; off < 32; off <<= 1) {
            float o = __shfl_up(incl, off);
            if (f >= off) incl += o;
        }
        float base = chE[k];
        preE[p0 + f] = base + incl - e;
        if (k == NCH - 1 && f == CH - 1) preE[N_ROWS] = base + incl;
    }

    float aez = chEZ[k * F_DIM + f];
    float az  = chZ [k * F_DIM + f];
    #pragma unroll 4
    for (int q = 0; q < CH; ++q) {
        int p = p0 + q;
        preEZ[(size_t)p * F_DIM + f] = aez;
        preZ [(size_t)p * F_DIM + f] = az;
        float e  = ed[p];
        float zv = z[(size_t)perm[p] * F_DIM + f];
        aez = fmaf(e, zv, aez);
        az += zv;
    }
    if (k == NCH - 1) {
        preEZ[(size_t)N_ROWS * F_DIM + f] = aez;
        preZ [(size_t)N_ROWS * F_DIM + f] = az;
    }
}

// ---------------------------------------------------------------------------
// K6: z2 = (es*sufEZ + preZ[c]) / (es*sufE + c) + z ; out = softmax(z2)
// 2 rows per 256-thread block.
// ---------------------------------------------------------------------------
__global__ __launch_bounds__(256) void k6_final(const float* __restrict__ z,
                                                const float* __restrict__ s,
                                                const int* __restrict__ cnt,
                                                const float* __restrict__ preEZ,
                                                const float* __restrict__ preZ,
                                                const float* __restrict__ preE,
                                                float* __restrict__ out) {
    __shared__ float redmx[4], redsum[4];
    int t = threadIdx.x;
    int grp = t >> 7;             // row within block
    int f = t & 127;
    int wave = t >> 6, lane = t & 63;
    int i = blockIdx.x * 2 + grp;

    float si = s[i];
    float es = expf(si);
    int   c  = cnt[i];

    float totE = preE[N_ROWS];
    float sufE = totE - preE[c];
    float D = fmaf(es, sufE, (float)c);

    float sufEZ = preEZ[(size_t)N_ROWS * F_DIM + f] - preEZ[(size_t)c * F_DIM + f];
    float num   = fmaf(es, sufEZ, preZ[(size_t)c * F_DIM + f]);
    float z2    = num / D + z[(size_t)i * F_DIM + f];

    float mx = z2;
    #pragma unroll
    for (int off = 32; off > 0; off >>= 1) mx = fmaxf(mx, __shfl_xor(mx, off));
    if (lane == 0) redmx[wave] = mx;
    __syncthreads();
    mx = fmaxf(redmx[grp * 2], redmx[grp * 2 + 1]);

    float ex = expf(z2 - mx);
    float sm = ex;
    #pragma unroll
    for (int off = 32; off > 0; off >>= 1) sm += __shfl_xor(sm, off);
    if (lane == 0) redsum[wave] = sm;
    __syncthreads();
    sm = redsum[grp * 2] + redsum[grp * 2 + 1];

    out[(size_t)i * F_DIM + f] = ex / sm;
}

// ---------------------------------------------------------------------------
extern "C" void kernel_launch(void* const* d_in, const int* in_sizes, int n_in,
                              void* d_out, int out_size, void* d_ws, size_t ws_size,
                              hipStream_t stream) {
    const float* x  = (const float*)d_in[0];
    const float* v  = (const float*)d_in[1];
    const float* g  = (const float*)d_in[2];
    const float* b  = (const float*)d_in[3];
    const float* aw = (const float*)d_in[4];
    float* out = (float*)d_out;

    float* wsf = (float*)d_ws;
    size_t off = 0;
    float* z     = wsf + off;  off += (size_t)N_ROWS * F_DIM;
    float* s     = wsf + off;  off += N_ROWS;
    float* d     = wsf + off;  off += N_ROWS;
    unsigned long long* keys = (unsigned long long*)(wsf + off);  off += 2 * N_ROWS;
    int*   rank  = (int*)(wsf + off);  off += N_ROWS;
    int*   cnt   = (int*)(wsf + off);  off += N_ROWS;
    int*   perm  = (int*)(wsf + off);  off += N_ROWS;
    float* ed    = wsf + off;  off += N_ROWS;
    float* preE  = wsf + off;  off += N_ROWS + 4;
    float* preEZ = wsf + off;  off += (size_t)(N_ROWS + 1) * F_DIM;
    float* preZ  = wsf + off;  off += (size_t)(N_ROWS + 1) * F_DIM;
    float* chEZ  = wsf + off;  off += NCH * F_DIM;
    float* chZ   = wsf + off;  off += NCH * F_DIM;
    float* chE   = wsf + off;  off += NCH;
    ushort_t* vh = (ushort_t*)(wsf + off);  off += (F_DIM * IN_DIM) / 2;
    ushort_t* vl = (ushort_t*)(wsf + off);  off += (F_DIM * IN_DIM) / 2;

    k1_prep<<<F_DIM, 64, 0, stream>>>(v, g, vh, vl);
    k2_mfma<<<N_ROWS / 32, 512, 0, stream>>>(x, vh, vl, b, aw, z, s, d, keys, rank, cnt);
    k4_rank<<<dim3(N_ROWS / 256, N_ROWS / K4T), 256, 0, stream>>>(keys, s, rank, cnt);
    k5a_scatter<<<N_ROWS / 256, 256, 0, stream>>>(d, rank, perm, ed);
    k5b_chunksum<<<NCH, 128, 0, stream>>>(z, perm, ed, chEZ, chZ, chE);
    k5c_scan<<<F_DIM + 1, 64, 0, stream>>>(chEZ, chZ, chE);
    k5d_prefix<<<NCH, 128, 0, stream>>>(z, perm, ed, chEZ, chZ, chE, preEZ, preZ, preE);
    k6_final<<<N_ROWS / 2, 256, 0, stream>>>(z, s, cnt, preEZ, preZ, preE, out);
}